// Round 21
// baseline (52.349 us; speedup 1.0000x reference)
//
#include <hip/hip_runtime.h>

// AttentionConvFull: grouped 1x1 QKV + 5x5 per-channel local attention, FUSED.
// B=4, H=W=56, C=OC=256, G=8, Cg=32, K=5, pad=2.
//
// R21 = R20 body with the qreg[8] array REMOVED (q re-read from qs LDS at
// use: 40 conflict-free b32 reads, ~230cy - noise). Goal: drop phase-C peak
// liveness from 72 to <=64 NATURALLY (no forced cap: still (256,3), cap 85,
// spill impossible). m69 bands: VGPR<=64 -> 8 waves/SIMD vs 4 at 65-128.
// R13-R15/R19 proved forced caps spill; R16 proved relp diet alone lands 72;
// this removes the next-cheapest 8 registers.
//
//   Stage:   x halo (12x12 px, 32 ch) -> xs LDS, coalesced float4, OOB zeroed.
//   Merged QKV pass (18 iters, 3 chains): weights demote to L1 reloads (fine).
//            k,v packed bf16x2 in one u32, overwriting xs in place (row's
//            only reader+writer is its owning half-wave; reads precede
//            writes; per-wave in-order DS => race-free). q*log2e -> qs (f32).
//   Phase C: monolithic 8-pixel row-streaming attention; q read from qs at
//            use; k,v,rel bf16-unpacked; native exp2 + rcp; single-pass
//            softmax (logits bounded, f32-safe).
// 2 barriers. LDS 26.6 KB.
//
// Register law (R1-R20): cap = 256/N for __launch_bounds__(256,N); no bounds
// => 64 cap. Forced caps below natural demand spill (R13/R14/R15/R19:
// WRITE 30-191MB vs 12.5 logical). launch_bounds 2nd arg is NOT a residency
// limiter (R20: (256,3) == (256,2) counters). Natural demand: phase C.
// Precision ledger: bf16 k,v + bf16 rel = 2.34e-2 measured; threshold 5.69e-2.

constexpr int TB = 4, TH = 56, TW = 56, TC = 256;
constexpr int G  = 8, CG = 32, PAD = 2;
constexpr int TILE = 8;
constexpr int HT = TILE + 2 * PAD;   // 12
constexpr int NT = TH / TILE;        // 7
constexpr int NPIX_HALO = HT * HT;   // 144
constexpr float LOG2E = 1.44269504088896340736f;

__global__ __launch_bounds__(256, 3)
void fused_attn_conv_kernel(const float* __restrict__ x,
                            const float* __restrict__ wq,
                            const float* __restrict__ wk,
                            const float* __restrict__ wv,
                            const float* __restrict__ rel,
                            const float* __restrict__ qemb,
                            float* __restrict__ out) {
    __shared__ float xs[NPIX_HALO][CG];    // 18 KB: x halo, then packed bf16(k,v)
    __shared__ float qs[TILE * TILE][CG];  // 8 KB: q*log2e for interior pixels

    const int bid  = blockIdx.x;
    const int g    = bid & 7;
    const int tile = bid >> 3;
    const int tj   = tile % NT;
    const int ti   = (tile / NT) % NT;
    const int b    = tile / (NT * NT);

    const int t  = threadIdx.x;
    const int c  = t & 31;
    const int p0 = t >> 5;

    const int oc = g * CG + c;           // global out-channel
    const int h0 = ti * TILE - PAD, w0 = tj * TILE - PAD;

    // ---- Stage: x halo -> xs, coalesced float4 (1152 float4 over 256 thr).
#pragma unroll
    for (int r = 0; r < 5; ++r) {
        const int f = t + r * 256;
        if (f < NPIX_HALO * CG / 4) {
            const int hp = f >> 3, c4 = f & 7;        // 8 float4 per pixel
            const int hi = hp / HT, hj = hp % HT;
            const int gh = h0 + hi, gw = w0 + hj;
            float4 val = make_float4(0.f, 0.f, 0.f, 0.f);
            if (gh >= 0 && gh < TH && gw >= 0 && gw < TW)
                val = *(const float4*)(x + (((size_t)b * TH + gh) * TW + gw) * TC
                                         + g * CG + c4 * 4);
            *(float4*)&xs[hp][c4 * 4] = val;
        }
    }

    __syncthreads();   // stage -> merged pass

    // ---- Merged QKV pass over all 144 halo pixels (R12 shape).
    {
        float wqr[CG], wkr[CG], wvr[CG];
        const float4* wqp = (const float4*)(wq + (size_t)oc * CG);
        const float4* wkp = (const float4*)(wk + (size_t)oc * CG);
        const float4* wvp = (const float4*)(wv + (size_t)oc * CG);
#pragma unroll
        for (int i = 0; i < CG / 4; ++i) {
            float4 a = wqp[i], bb = wkp[i], cc = wvp[i];
            wqr[4*i+0]=a.x; wqr[4*i+1]=a.y; wqr[4*i+2]=a.z; wqr[4*i+3]=a.w;
            wkr[4*i+0]=bb.x; wkr[4*i+1]=bb.y; wkr[4*i+2]=bb.z; wkr[4*i+3]=bb.w;
            wvr[4*i+0]=cc.x; wvr[4*i+1]=cc.y; wvr[4*i+2]=cc.z; wvr[4*i+3]=cc.w;
        }
        const float qe = qemb[oc];

#pragma unroll 1   // rolled: keeps liveness flat
        for (int it = 0; it < NPIX_HALO / 8; ++it) {
            const int hp = it * 8 + p0;
            const int hi = hp / HT, hj = hp % HT;
            const float4* xp = (const float4*)&xs[hp][0];
            float aq = qe, ak = 0.f, av = 0.f;
#pragma unroll
            for (int i = 0; i < CG / 4; ++i) {
                const float4 xv = xp[i];   // LDS broadcast within half-wave
                aq = fmaf(wqr[4*i+0], xv.x, aq); ak = fmaf(wkr[4*i+0], xv.x, ak); av = fmaf(wvr[4*i+0], xv.x, av);
                aq = fmaf(wqr[4*i+1], xv.y, aq); ak = fmaf(wkr[4*i+1], xv.y, ak); av = fmaf(wvr[4*i+1], xv.y, av);
                aq = fmaf(wqr[4*i+2], xv.z, aq); ak = fmaf(wkr[4*i+2], xv.z, ak); av = fmaf(wvr[4*i+2], xv.z, av);
                aq = fmaf(wqr[4*i+3], xv.w, aq); ak = fmaf(wkr[4*i+3], xv.w, ak); av = fmaf(wvr[4*i+3], xv.w, av);
            }
            // pack k,v -> bf16 (round-half-up) in one u32; overwrite xs row
            // in place (all reads of this row happened above, same lanes).
            const unsigned kb = __float_as_uint(ak) + 0x8000u;
            const unsigned vb = __float_as_uint(av) + 0x8000u;
            ((unsigned*)&xs[hp][0])[c] = (kb >> 16) | (vb & 0xffff0000u);
            if (hi >= PAD && hi < PAD + TILE && hj >= PAD && hj < PAD + TILE)
                qs[(hi - PAD) * TILE + (hj - PAD)][c] = aq * LOG2E;
        }
    }

    // rel row -> 13 packed bf16 pairs (even idx = low half, odd = high half)
    unsigned relp[13];
    {
        const float* rp = rel + (size_t)oc * 25;
#pragma unroll
        for (int i = 0; i < 12; ++i) {
            const unsigned lo = __float_as_uint(rp[2 * i])     + 0x8000u;
            const unsigned hi = __float_as_uint(rp[2 * i + 1]) + 0x8000u;
            relp[i] = (lo >> 16) | (hi & 0xffff0000u);
        }
        relp[12] = (__float_as_uint(rp[24]) + 0x8000u) >> 16;
    }

    __syncthreads();   // merged pass -> C

    // ---- Phase C: monolithic row-streaming attention (xs holds bf16 k,v).
    //      q is read from qs at use (saves the qreg[8] array: -8 VGPR).
    float s_[8], a_[8];
#pragma unroll
    for (int ii = 0; ii < 8; ++ii) { s_[ii] = 0.f; a_[ii] = 0.f; }

    const unsigned* kvp = (const unsigned*)&xs[0][0];
#pragma unroll
    for (int h = 0; h < HT; ++h) {
        float kr[5], vr[5];
#pragma unroll
        for (int j = 0; j < 5; ++j) {
            const unsigned u = kvp[(h * HT + p0 + j) * CG + c];
            kr[j] = __uint_as_float(u << 16);          // bf16 k -> f32
            vr[j] = __uint_as_float(u & 0xffff0000u);  // bf16 v -> f32
        }
#pragma unroll
        for (int ii = 0; ii < 8; ++ii) {
            const int di = h - ii;               // compile-time after unroll
            if (di >= 0 && di < 5) {
                const float qv = qs[ii * TILE + p0][c];   // LDS, conflict-free
#pragma unroll
                for (int j = 0; j < 5; ++j) {
                    const int idx = di * 5 + j;  // compile-time
                    const unsigned ru = relp[idx >> 1];
                    const float rl = __uint_as_float((idx & 1) ? (ru & 0xffff0000u)
                                                               : (ru << 16));
                    const float e = __builtin_amdgcn_exp2f(qv * (kr[j] + rl));
                    s_[ii] += e;
                    a_[ii] = fmaf(e, vr[j], a_[ii]);
                }
            }
        }
    }

#pragma unroll
    for (int ii = 0; ii < 8; ++ii) {
        const int gh = ti * TILE + ii, gw = tj * TILE + p0;
        out[(((size_t)b * TH + gh) * TW + gw) * TC + g * CG + c] =
            a_[ii] * __builtin_amdgcn_rcpf(s_[ii]);
    }
}

extern "C" void kernel_launch(void* const* d_in, const int* in_sizes, int n_in,
                              void* d_out, int out_size, void* d_ws, size_t ws_size,
                              hipStream_t stream) {
    const float* x    = (const float*)d_in[0];
    const float* wq   = (const float*)d_in[1];
    const float* wk   = (const float*)d_in[2];
    const float* wv   = (const float*)d_in[3];
    const float* rel  = (const float*)d_in[4];
    const float* qemb = (const float*)d_in[5];
    float* out = (float*)d_out;

    const int nblocks = TB * NT * NT * G;   // 4*7*7*8 = 1568
    hipLaunchKernelGGL(fused_attn_conv_kernel, dim3(nblocks), dim3(256), 0, stream,
                       x, wq, wk, wv, rel, qemb, out);
}